// Round 11
// baseline (232.293 us; speedup 1.0000x reference)
//
#include <hip/hip_runtime.h>

#define HH 512
#define WW 512
#define NPIX (HH*WW)      // 2^18
#define BATCH 16
#define NIMG 32           // 16 ref + 16 tgt
#define PW 544            // padded lum row stride (16-px guard each side)
#define PAD 16

typedef unsigned char uchar;
typedef unsigned long long u64;

// ---------------- Stage 1: luminance -> padded layout ----------
__global__ __launch_bounds__(256) void k_lum(const float4* __restrict__ ref,
                                             const float4* __restrict__ tgt,
                                             float4* __restrict__ lum) {
    int idx = blockIdx.x * 256 + threadIdx.x;     // NIMG * NPIX/4 threads
    int img = idx >> 16;                          // NPIX/4 = 65536
    int p4 = idx & 65535;
    int y = p4 >> 7;                              // 128 float4 per image row
    int x4 = p4 & 127;
    const float4* src = (img < BATCH) ? (ref + (size_t)img * 3 * 65536)
                                      : (tgt + (size_t)(img - BATCH) * 3 * 65536);
    float4 r = src[p4];
    float4 g = src[65536 + p4];
    float4 b = src[131072 + p4];
    float4 o;
    o.x = 0.299f * r.x + 0.587f * g.x + 0.114f * b.x;
    o.y = 0.299f * r.y + 0.587f * g.y + 0.114f * b.y;
    o.z = 0.299f * r.z + 0.587f * g.z + 0.114f * b.z;
    o.w = 0.299f * r.w + 0.587f * g.w + 0.114f * b.w;
    lum[(size_t)img * (PW * PW / 4) + (size_t)(y + PAD) * (PW / 4) + (PAD / 4) + x4] = o;
}

// ---- Stages 2+3+4: barrier-free wave-pipelined strip kernel, zero shuffles --
// One wave = 52 output cols x 32 output rows. All neighbor values come from
// direct loads on the padded lum (imm offsets off 2 pointers), with a depth-1
// software pipeline (cur/next). E/hE/p/v as ballot bitmasks; 7-deep moment
// ring. No LDS, no __syncthreads, no DS ops in the steady loop.

__inline__ __device__ float wave_reduce(float v) {
#pragma unroll
    for (int o = 32; o > 0; o >>= 1) v += __shfl_down(v, o);
    return v;
}

__global__ __launch_bounds__(256) void k_strip(const float* __restrict__ lum_p,
                                               uchar* __restrict__ Mo_g,
                                               double* __restrict__ acc) {
    int lane = threadIdx.x & 63;
    int gw = blockIdx.x * 4 + (threadIdx.x >> 6);   // 0..5119
    int img = gw / 160;                             // 10 sx * 16 sy
    int rem = gw - img * 160;
    int sy = rem / 10;
    int sx = rem - sy * 10;
    int r0 = sy << 5;          // first output row
    int c0 = sx * 52;
    int col = c0 + lane - 6;
    bool colok = (unsigned)col < WW;

    const float* LB = lum_p + (size_t)img * (PW * PW) + (size_t)PAD * PW + PAD;
    const float* base0 = LB + col;                  // col index (may be -9..525)
    uchar* Mo = Mo_g + (size_t)img * NPIX;

    // rolling lum triples: slot0=oldest(L-3) .. slot3=newest(L)
    float tm0 = 0, tm1 = 0, tm2 = 0, tm3 = 0;
    float tc0 = 0, tc1 = 0, tc2 = 0, tc3 = 0;
    float tp0 = 0, tp1 = 0, tp2 = 0, tp3 = 0;
    unsigned eb = 0, hb = 0, pbm = 0, vbm = 0;

#define SHIFT3() { tm0 = tm1; tc0 = tc1; tp0 = tp1; \
                   tm1 = tm2; tc1 = tc2; tp1 = tp2; \
                   tm2 = tm3; tc2 = tc3; tp2 = tp3; }

#define SOBEL_E(Lr) { \
    float gx = (tp1 - tm1) + 2.0f * (tp2 - tm2) + (tp3 - tm3); \
    float gy = (tm3 + 2.0f * tc3 + tp3) - (tm1 + 2.0f * tc1 + tp1); \
    float grad = sqrtf(gx * gx + gy * gy + 1e-12f); \
    bool e = (grad > 0.1f) && colok && ((unsigned)((Lr) - 1) < HH); \
    u64 ebal = __ballot(e); \
    eb = (eb << 1) | (e ? 1u : 0u); \
    unsigned hE5 = (unsigned)((ebal << 2) >> lane) & 0x1Fu; \
    hb = (hb << 1) | (hE5 ? 1u : 0u); }

    // ---- pre-issue steady j=0 loads (row r0, cols +-1; row r0-3, cols +-2,+-3)
    const float* pN = base0 + (ptrdiff_t)r0 * PW;
    float cA = pN[-1], cB = pN[0], cC = pN[1];
    const float* pM0 = pN - 3 * PW;
    float cx0 = pM0[-3], cx1 = pM0[-2], cx5 = pM0[2], cx6 = pM0[3];
    pN += PW;

    // ---- pre-roll + warm: rows r0-6 .. r0-1 (direct loads) ----
    {
        const float* pR = base0 + (ptrdiff_t)(r0 - 6) * PW;
        for (int q = 0; q < 2; ++q) {
            SHIFT3();
            tm3 = pR[-1]; tc3 = pR[0]; tp3 = pR[1];
            pR += PW;
        }
        for (int q = 0; q < 4; ++q) {
            int Lr = r0 - 4 + q;
            SHIFT3();
            tm3 = pR[-1]; tc3 = pR[0]; tp3 = pR[1];
            pR += PW;
            SOBEL_E(Lr);
        }
    }

    // ---- steady: 42 iterations, ring unrolled x7, depth-1 load pipeline ----
    float r1p[7], r2p[7], r1v[7], r2v[7];
    unsigned rcn[7];
    unsigned cnt_acc = 0;
    float a1p = 0, a2p = 0, a1v = 0, a2v = 0;
    float c0a = 0, c1a = 0, c2a = 0, c3a = 0;

    for (int o6 = 0; o6 < 6; ++o6) {
#pragma unroll
        for (int u = 0; u < 7; ++u) {
            int j = o6 * 7 + u;
            int Lr = r0 + j;

            // issue loads for iteration j+1
            float nA = pN[-1], nB = pN[0], nC = pN[1];
            const float* pM = pN - 3 * PW;
            float nx0 = pM[-3], nx1 = pM[-2], nx5 = pM[2], nx6 = pM[3];

            // consume current row
            SHIFT3();
            tm3 = cA; tc3 = cB; tp3 = cC;
            SOBEL_E(Lr);

            int m = Lr - 3;
            bool ed = (hb & 0x1Fu) != 0;
            bool e3 = ((eb >> 2) & 1u) != 0;
            bool mrowok = (unsigned)m < HH;
            bool pp = ed && !e3 && mrowok && colok;
            bool vv = (!ed) && mrowok && colok;
            u64 pb = __ballot(pp);
            u64 vb = __ballot(vv);
            pbm = (pbm << 1) | (pp ? 1u : 0u);
            vbm = (vbm << 1) | (vv ? 1u : 0u);

            float xx0 = cx0;   // col-3 of row m
            float xx1 = cx1;   // col-2
            float xx2 = tm0;   // col-1 (rolling)
            float xx3 = tc0;   // col
            float xx4 = tp0;   // col+1
            float xx5 = cx5;   // col+2
            float xx6 = cx6;   // col+3
            unsigned pw = (unsigned)((pb << 3) >> lane) & 0x7Fu;
            unsigned vw = (unsigned)((vb << 3) >> lane) & 0x7Fu;
            unsigned cnt_new = (unsigned)__popc(pw) | ((unsigned)__popc(vw) << 8);
            float s1p = 0, s2p = 0, s1v = 0, s2v = 0;
#define TAP(i, xi) { \
            float pxi = ((pw >> (i)) & 1u) ? (xi) : 0.0f; \
            float vxi = ((vw >> (i)) & 1u) ? (xi) : 0.0f; \
            s1p += pxi; s2p = fmaf(pxi, (xi), s2p); \
            s1v += vxi; s2v = fmaf(vxi, (xi), s2v); }
            TAP(0, xx0) TAP(1, xx1) TAP(2, xx2) TAP(3, xx3)
            TAP(4, xx4) TAP(5, xx5) TAP(6, xx6)
#undef TAP

            if (j >= 7) {   // slide out row m-7
                cnt_acc -= rcn[u];
                a1p -= r1p[u]; a2p -= r2p[u]; a1v -= r1v[u]; a2v -= r2v[u];
            }
            cnt_acc += cnt_new;
            a1p += s1p; a2p += s2p; a1v += s1v; a2v += s2v;
            rcn[u] = cnt_new; r1p[u] = s1p; r2p[u] = s2p; r1v[u] = s1v; r2v[u] = s2v;

            if (j >= 3 && j <= 34) {   // write prox byte for owned row m
                if (lane >= 6 && lane <= 57 && colok)
                    Mo[(size_t)m * WW + col] = (uchar)(pp ? 1 : 0);
            }
            if (j >= 6 && j <= 37) {   // output row y = Lr-6
                float mp0 = (float)((pbm >> 3) & 1u);
                float mb0 = (float)((vbm >> 3) & 1u);
                if (lane < 6 || lane > 57) { mp0 = 0.0f; mb0 = 0.0f; }
                float cpf = (float)(cnt_acc & 0xFFu);
                float cvf = (float)((cnt_acc >> 8) & 0xFFu);
                float rCp = __builtin_amdgcn_rcpf(fmaxf(cpf, 1.0f));
                float meanp = a1p * rCp;
                float varp = fmaxf(a2p * rCp - meanp * meanp, 0.0f);
                float rCb = __builtin_amdgcn_rcpf(fmaxf(cvf, 1.0f));
                float meanb = a1v * rCb;
                float varb = fmaxf(a2v * rCb - meanb * meanb, 0.0f);
                c0a += varp * mp0; c1a += mp0;
                c2a += varb * mb0; c3a += mb0;
            }

            // rotate pipeline
            cA = nA; cB = nB; cC = nC;
            cx0 = nx0; cx1 = nx1; cx5 = nx5; cx6 = nx6;
            pN += PW;
        }
    }

    c0a = wave_reduce(c0a); c1a = wave_reduce(c1a);
    c2a = wave_reduce(c2a); c3a = wave_reduce(c3a);
    if (lane == 0) {
        atomicAdd(&acc[img * 4 + 0], (double)c0a);
        atomicAdd(&acc[img * 4 + 1], (double)c1a);
        atomicAdd(&acc[img * 4 + 2], (double)c2a);
        atomicAdd(&acc[img * 4 + 3], (double)c3a);
    }
}

// ---------------- Stage 5a: per-image ringing flags ----------------
__global__ void k_flags(const double* __restrict__ acc, float* __restrict__ flags) {
    int i = threadIdx.x;
    if (i >= NIMG) return;
    const double* a = acc + (size_t)i * 4;
    double vp = a[0] / fmax(a[1], 1.0);
    double vb = a[2] / fmax(a[3], 1.0);
    flags[i] = ((vp / (vb + 1e-12)) > 2.0) ? 1.0f : 0.0f;
}

// ---------------- Stage 5b: output from prox byte masks ----------------
__global__ __launch_bounds__(256) void k_out(const uchar4* __restrict__ M,
                                             const float* __restrict__ flags,
                                             float4* __restrict__ out) {
    int idx = blockIdx.x * 256 + threadIdx.x;   // BATCH * NPIX/4 threads
    int b = idx >> 16;
    int p = idx & 65535;
    float fr = flags[b], ft = flags[b + BATCH];
    uchar4 mr = M[(size_t)b * 65536 + p];
    uchar4 mt = M[(size_t)(b + BATCH) * 65536 + p];
    float4 o;
    o.x = fmaxf((mt.x ? ft : 0.0f) - (mr.x ? fr : 0.0f), 0.0f);
    o.y = fmaxf((mt.y ? ft : 0.0f) - (mr.y ? fr : 0.0f), 0.0f);
    o.z = fmaxf((mt.z ? ft : 0.0f) - (mr.z ? fr : 0.0f), 0.0f);
    o.w = fmaxf((mt.w ? ft : 0.0f) - (mr.w ? fr : 0.0f), 0.0f);
    out[idx] = o;
}

extern "C" void kernel_launch(void* const* d_in, const int* in_sizes, int n_in,
                              void* d_out, int out_size, void* d_ws, size_t ws_size,
                              hipStream_t stream) {
    const float* ref = (const float*)d_in[0];
    const float* tgt = (const float*)d_in[1];
    float* out = (float*)d_out;

    char* ws = (char*)d_ws;
    double* acc = (double*)ws;                       // 32*4 doubles = 1 KB
    float* flags = (float*)(ws + 1024);              // 32 floats
    float* lum = (float*)(ws + 2048);                // 32 * 544*544 * 4 = 37.9 MB
    size_t lum_bytes = (size_t)NIMG * PW * PW * 4;
    uchar* Mo = (uchar*)(ws + 2048 + lum_bytes);     // 8 MB prox bytes

    (void)hipMemsetAsync(acc, 0, NIMG * 4 * sizeof(double), stream);
    (void)hipMemsetAsync(lum, 0, lum_bytes, stream); // zero guards (interior overwritten)

    int nAll = NIMG * NPIX;          // 8388608
    k_lum<<<nAll / 4 / 256, 256, 0, stream>>>((const float4*)ref, (const float4*)tgt, (float4*)lum);
    k_strip<<<1280, 256, 0, stream>>>(lum, Mo, acc);   // 5120 waves
    k_flags<<<1, 64, 0, stream>>>(acc, flags);
    k_out<<<BATCH * NPIX / 4 / 256, 256, 0, stream>>>((const uchar4*)Mo, flags, (float4*)out);
}